// Round 1
// baseline (2242.884 us; speedup 1.0000x reference)
//
#include <hip/hip_runtime.h>
#include <hip/hip_bf16.h>
#include <cstdint>
#include <cstddef>

#define DIM 5120
#define NH 40
#define HD 128
#define S_LEN 4096
#define L_LEN 512
#define CBATCH 2            // 2*B (cond + uncond)
#define MQ (CBATCH*S_LEN)   // 8192 rows of hidden
#define ML (CBATCH*L_LEN)   // 1024 rows of context

typedef unsigned short ushort_t;
typedef __bf16 bf16x8 __attribute__((ext_vector_type(8)));
typedef float f32x4 __attribute__((ext_vector_type(4)));

__device__ __forceinline__ float bf2f(ushort_t u) {
  union { unsigned u; float f; } c; c.u = ((unsigned)u) << 16; return c.f;
}
__device__ __forceinline__ ushort_t f2bf(float f) {
  union { float f; unsigned u; } c; c.f = f;
  unsigned r = c.u + 0x7fffu + ((c.u >> 16) & 1u);
  return (ushort_t)(r >> 16);
}

__device__ __forceinline__ void load_lds16(const void* g, void* l) {
  __builtin_amdgcn_global_load_lds(
      (const __attribute__((address_space(1))) void*)g,
      (__attribute__((address_space(3))) void*)l, 16, 0, 0);
}

// ---------------- fp32 -> bf16 convert ----------------
__global__ __launch_bounds__(256) void cvt_f32_bf16(const float* __restrict__ in,
                                                    ushort_t* __restrict__ out, int n4) {
  int i = blockIdx.x * 256 + threadIdx.x;
  if (i >= n4) return;
  float4 v = *(const float4*)(in + 4ull * (size_t)i);
  ushort4 o;
  o.x = f2bf(v.x); o.y = f2bf(v.y); o.z = f2bf(v.z); o.w = f2bf(v.w);
  *(ushort4*)(out + 4ull * (size_t)i) = o;
}

// ---------------- GEMM: C[M,N] = A[M,K] @ W[N,K]^T + bias ----------------
// m97 structure: 128x128 tile, BK=32, 4 waves (2x2), 4x4 16x16x32 frags per wave.
template <int OUT_F32>
__global__ __launch_bounds__(256) void gemm_bt(const ushort_t* __restrict__ A,
                                               const ushort_t* __restrict__ W,
                                               const float* __restrict__ bias,
                                               void* __restrict__ Cout,
                                               int M, int N, int K) {
  __shared__ ushort_t sA[128 * 32];
  __shared__ ushort_t sB[128 * 32];
  const int tid = threadIdx.x;
  const int w = tid >> 6, lane = tid & 63;
  const int g = lane >> 4, c = lane & 15;
  const int ntn = N >> 7;
  const int nwg = gridDim.x;
  int bid = blockIdx.x;
  bid = (bid & 7) * (nwg >> 3) + (bid >> 3);   // XCD swizzle (nwg % 8 == 0 by construction)
  const int tm = bid / ntn, tn = bid % ntn;
  const size_t m0 = (size_t)tm * 128, n0 = (size_t)tn * 128;
  const int wr = (w >> 1) * 64, wc = (w & 1) * 64;

  f32x4 acc[4][4] = {};

  const ushort_t* Abase = A + m0 * (size_t)K;
  const ushort_t* Bbase = W + n0 * (size_t)K;

  for (int k0 = 0; k0 < K; k0 += 32) {
    __syncthreads();   // previous iteration's LDS reads complete
#pragma unroll
    for (int i = 0; i < 2; ++i) {
      int gid = i * 256 + tid;           // 512 16B-chunks per 128x32 tile
      int row = gid >> 2, colE = (gid & 3) << 3;
      load_lds16(Abase + (size_t)row * K + k0 + colE, sA + i * 2048 + w * 512);
      load_lds16(Bbase + (size_t)row * K + k0 + colE, sB + i * 2048 + w * 512);
    }
    __syncthreads();   // staging landed (compiler drains vmcnt before barrier)
    bf16x8 a[4], b[4];
#pragma unroll
    for (int m = 0; m < 4; ++m)
      a[m] = *(const bf16x8*)(sA + (wr + m * 16 + c) * 32 + g * 8);
#pragma unroll
    for (int n = 0; n < 4; ++n)
      b[n] = *(const bf16x8*)(sB + (wc + n * 16 + c) * 32 + g * 8);
#pragma unroll
    for (int m = 0; m < 4; ++m)
#pragma unroll
      for (int n = 0; n < 4; ++n)
        acc[m][n] = __builtin_amdgcn_mfma_f32_16x16x32_bf16(a[m], b[n], acc[m][n], 0, 0, 0);
  }

  // epilogue: C/D layout col=lane&15, row=(lane>>4)*4+reg
#pragma unroll
  for (int m = 0; m < 4; ++m) {
#pragma unroll
    for (int n = 0; n < 4; ++n) {
      size_t gm = m0 + wr + m * 16 + g * 4;
      size_t gn = n0 + wc + n * 16 + c;
      float bn = bias[gn];
#pragma unroll
      for (int r = 0; r < 4; ++r) {
        float v = acc[m][n][r] + bn;
        if (OUT_F32) ((float*)Cout)[(gm + r) * (size_t)N + gn] = v;
        else         ((ushort_t*)Cout)[(gm + r) * (size_t)N + gn] = f2bf(v);
      }
    }
  }
}

// ---------------- RMSNorm (in place over ncols of each row) ----------------
__global__ __launch_bounds__(256) void rmsnorm_rows(ushort_t* __restrict__ x,
                                                    const float* __restrict__ gw,
                                                    int ncols, int stride) {
  const int row = blockIdx.x;
  ushort_t* p = x + (size_t)row * stride;
  const int tid = threadIdx.x;
  const int nch = ncols >> 3;
  float ss = 0.f;
  for (int ci = tid; ci < nch; ci += 256) {
    bf16x8 v = *(const bf16x8*)(p + ci * 8);
#pragma unroll
    for (int j = 0; j < 8; ++j) { float f = (float)v[j]; ss += f * f; }
  }
#pragma unroll
  for (int off = 1; off < 64; off <<= 1) ss += __shfl_xor(ss, off);
  __shared__ float sred[4];
  if ((tid & 63) == 0) sred[tid >> 6] = ss;
  __syncthreads();
  float tot = sred[0] + sred[1] + sred[2] + sred[3];
  float inv = rsqrtf(tot / (float)ncols + 1e-6f);
  for (int ci = tid; ci < nch; ci += 256) {
    bf16x8 v = *(const bf16x8*)(p + ci * 8);
    bf16x8 ov;
#pragma unroll
    for (int j = 0; j < 8; ++j) {
      float f = (float)v[j];
      ushort_t ob = f2bf(f * inv * gw[ci * 8 + j]);
      ov[j] = *(__bf16*)&ob;
    }
    *(bf16x8*)(p + ci * 8) = ov;
  }
}

// ---------------- V transpose: kv[:, DIM + h*HD + d] -> vt[bh][d][l] ----------------
__global__ __launch_bounds__(256) void transpose_v(const ushort_t* __restrict__ kv,
                                                   ushort_t* __restrict__ vt) {
  const int bh = blockIdx.y, b = bh / NH, h = bh % NH;
  const int l0 = blockIdx.x * 32;
  const ushort_t* src = kv + (size_t)b * L_LEN * (2 * DIM) + DIM + (size_t)h * HD;
  ushort_t* dst = vt + (size_t)bh * HD * L_LEN;
  __shared__ ushort_t tile[32][HD + 16];   // stride 288B: 16B-aligned, banks spread
  const int tid = threadIdx.x;
#pragma unroll
  for (int i = 0; i < 2; ++i) {
    int gid = i * 256 + tid;
    int r = gid >> 4, ce = (gid & 15) << 3;
    *(bf16x8*)(&tile[r][ce]) = *(const bf16x8*)(src + (size_t)(l0 + r) * (2 * DIM) + ce);
  }
  __syncthreads();
#pragma unroll
  for (int i = 0; i < 2; ++i) {
    int gid = i * 256 + tid;
    int d = gid >> 2, le = (gid & 3) << 3;
    bf16x8 v;
#pragma unroll
    for (int j = 0; j < 8; ++j) v[j] = *(__bf16*)&tile[le + j][d];
    *(bf16x8*)(dst + (size_t)d * L_LEN + l0 + le) = v;
  }
}

// ---------------- fused cross-attention ----------------
// grid: (S_LEN/64, CBATCH*NH); 4 waves, 16 q-rows per wave; flash over L in 32-tiles.
__global__ __launch_bounds__(256) void attn_fwd(const ushort_t* __restrict__ q,
                                                const ushort_t* __restrict__ kv,
                                                const ushort_t* __restrict__ vt,
                                                ushort_t* __restrict__ out) {
  const int bh = blockIdx.y, b = bh / NH, h = bh % NH;
  const int sBase = blockIdx.x * 64;
  const int tid = threadIdx.x, w = tid >> 6, lane = tid & 63;
  const int g = lane >> 4, c = lane & 15;
  const int qr0 = sBase + w * 16;

  const ushort_t* qbase = q + ((size_t)b * S_LEN + qr0) * DIM + (size_t)h * HD;
  const ushort_t* kbase = kv + (size_t)b * L_LEN * (2 * DIM) + (size_t)h * HD;
  const ushort_t* vbase = vt + (size_t)bh * HD * L_LEN;

  bf16x8 qa[4];
#pragma unroll
  for (int kk = 0; kk < 4; ++kk)
    qa[kk] = *(const bf16x8*)(qbase + (size_t)c * DIM + kk * 32 + g * 8);

  f32x4 oacc[8] = {};
  float mrun[4], lrun[4];
#pragma unroll
  for (int r = 0; r < 4; ++r) { mrun[r] = -3.0e38f; lrun[r] = 0.f; }

  const float sc = 0.08838834764831845f * 1.4426950408889634f;  // 1/sqrt(128) * log2(e)

  __shared__ ushort_t sP[4][16][32];

  for (int l0 = 0; l0 < L_LEN; l0 += 32) {
    f32x4 sv0 = {0.f, 0.f, 0.f, 0.f}, sv1 = {0.f, 0.f, 0.f, 0.f};
#pragma unroll
    for (int kk = 0; kk < 4; ++kk) {
      bf16x8 kb0 = *(const bf16x8*)(kbase + (size_t)(l0 + c) * (2 * DIM) + kk * 32 + g * 8);
      sv0 = __builtin_amdgcn_mfma_f32_16x16x32_bf16(qa[kk], kb0, sv0, 0, 0, 0);
      bf16x8 kb1 = *(const bf16x8*)(kbase + (size_t)(l0 + 16 + c) * (2 * DIM) + kk * 32 + g * 8);
      sv1 = __builtin_amdgcn_mfma_f32_16x16x32_bf16(qa[kk], kb1, sv1, 0, 0, 0);
    }
    float alpha[4];
#pragma unroll
    for (int r = 0; r < 4; ++r) {
      float a0 = sv0[r] * sc, a1 = sv1[r] * sc;
      float v = fmaxf(a0, a1);
      v = fmaxf(v, __shfl_xor(v, 1));
      v = fmaxf(v, __shfl_xor(v, 2));
      v = fmaxf(v, __shfl_xor(v, 4));
      v = fmaxf(v, __shfl_xor(v, 8));
      float mn = fmaxf(mrun[r], v);
      alpha[r] = exp2f(mrun[r] - mn);
      float p0 = exp2f(a0 - mn), p1 = exp2f(a1 - mn);
      float ps = p0 + p1;
      ps += __shfl_xor(ps, 1);
      ps += __shfl_xor(ps, 2);
      ps += __shfl_xor(ps, 4);
      ps += __shfl_xor(ps, 8);
      lrun[r] = lrun[r] * alpha[r] + ps;
      mrun[r] = mn;
      sP[w][g * 4 + r][c] = f2bf(p0);
      sP[w][g * 4 + r][16 + c] = f2bf(p1);
    }
#pragma unroll
    for (int t = 0; t < 8; ++t)
#pragma unroll
      for (int r = 0; r < 4; ++r) oacc[t][r] *= alpha[r];
    bf16x8 pa = *(const bf16x8*)(&sP[w][c][g * 8]);
#pragma unroll
    for (int t = 0; t < 8; ++t) {
      bf16x8 vb = *(const bf16x8*)(vbase + (size_t)(t * 16 + c) * L_LEN + l0 + g * 8);
      oacc[t] = __builtin_amdgcn_mfma_f32_16x16x32_bf16(pa, vb, oacc[t], 0, 0, 0);
    }
  }

  ushort_t* obase = out + ((size_t)b * S_LEN + qr0) * DIM + (size_t)h * HD;
#pragma unroll
  for (int t = 0; t < 8; ++t)
#pragma unroll
    for (int r = 0; r < 4; ++r) {
      float v = oacc[t][r] / lrun[r];
      obase[(size_t)(g * 4 + r) * DIM + t * 16 + c] = f2bf(v);
    }
}

// ---------------- host ----------------
extern "C" void kernel_launch(void* const* d_in, const int* in_sizes, int n_in,
                              void* d_out, int out_size, void* d_ws, size_t ws_size,
                              hipStream_t stream) {
  (void)in_sizes; (void)n_in; (void)out_size; (void)ws_size;
  const float* hidden_c = (const float*)d_in[0];
  const float* hidden_u = (const float*)d_in[1];
  const float* ctx_c    = (const float*)d_in[2];
  const float* ctx_u    = (const float*)d_in[3];
  const float* Wq  = (const float*)d_in[4];
  const float* bq  = (const float*)d_in[5];
  const float* Wkv = (const float*)d_in[6];
  const float* bkv = (const float*)d_in[7];
  const float* gq  = (const float*)d_in[8];
  const float* gk  = (const float*)d_in[9];
  const float* Wo  = (const float*)d_in[10];
  const float* bo  = (const float*)d_in[11];

  char* ws = (char*)d_ws;
  size_t off = 0;
  auto alloc = [&](size_t bytes) {
    char* p = ws + off; off += (bytes + 255) & ~(size_t)255; return p;
  };
  ushort_t* hbf  = (ushort_t*)alloc((size_t)MQ * DIM * 2);      // hidden bf16; reused as attn-out
  ushort_t* cbf  = (ushort_t*)alloc((size_t)ML * DIM * 2);      // context bf16
  ushort_t* wqb  = (ushort_t*)alloc((size_t)DIM * DIM * 2);     // Wq bf16; reused for Wo
  ushort_t* wkvb = (ushort_t*)alloc((size_t)2 * DIM * DIM * 2); // Wkv bf16
  ushort_t* kvb  = (ushort_t*)alloc((size_t)ML * 2 * DIM * 2);  // kv output bf16
  ushort_t* vtb  = (ushort_t*)alloc((size_t)CBATCH * NH * HD * L_LEN * 2);
  ushort_t* qb   = (ushort_t*)d_out;  // q bf16 lives in d_out until the final GEMM

  auto cvt = [&](const float* in, ushort_t* o, size_t n) {
    int n4 = (int)(n >> 2);
    cvt_f32_bf16<<<dim3((n4 + 255) / 256), dim3(256), 0, stream>>>(in, o, n4);
  };
  cvt(hidden_c, hbf, (size_t)S_LEN * DIM);
  cvt(hidden_u, hbf + (size_t)S_LEN * DIM, (size_t)S_LEN * DIM);
  cvt(ctx_c, cbf, (size_t)L_LEN * DIM);
  cvt(ctx_u, cbf + (size_t)L_LEN * DIM, (size_t)L_LEN * DIM);
  cvt(Wq, wqb, (size_t)DIM * DIM);
  cvt(Wkv, wkvb, (size_t)2 * DIM * DIM);

  // Q = hidden @ Wq^T + bq  -> qb (bf16, in d_out space)
  gemm_bt<0><<<dim3((MQ / 128) * (DIM / 128)), dim3(256), 0, stream>>>(
      hbf, wqb, bq, (void*)qb, MQ, DIM, DIM);
  // KV = context @ Wkv^T + bkv -> kvb
  gemm_bt<0><<<dim3((ML / 128) * ((2 * DIM) / 128)), dim3(256), 0, stream>>>(
      cbf, wkvb, bkv, (void*)kvb, ML, 2 * DIM, DIM);
  // Wo -> bf16 (reuses wqb; stream-ordered after Q GEMM)
  cvt(Wo, wqb, (size_t)DIM * DIM);

  rmsnorm_rows<<<dim3(MQ), dim3(256), 0, stream>>>(qb, gq, DIM, DIM);
  rmsnorm_rows<<<dim3(ML), dim3(256), 0, stream>>>(kvb, gk, DIM, 2 * DIM);
  transpose_v<<<dim3(L_LEN / 32, CBATCH * NH), dim3(256), 0, stream>>>(kvb, vtb);

  attn_fwd<<<dim3(S_LEN / 64, CBATCH * NH), dim3(256), 0, stream>>>(qb, kvb, vtb, hbf);

  // out = attn_out @ Wo^T + bo -> d_out (fp32)
  gemm_bt<1><<<dim3((MQ / 128) * (DIM / 128)), dim3(256), 0, stream>>>(
      hbf, wqb, bo, d_out, MQ, DIM, DIM);
}

// Round 2
// 1836.089 us; speedup vs baseline: 1.2216x; 1.2216x over previous
//
#include <hip/hip_runtime.h>
#include <hip/hip_bf16.h>
#include <cstdint>
#include <cstddef>

#define DIM 5120
#define NH 40
#define HD 128
#define S_LEN 4096
#define L_LEN 512
#define CBATCH 2            // 2*B (cond + uncond)
#define MQ (CBATCH*S_LEN)   // 8192 rows of hidden
#define ML (CBATCH*L_LEN)   // 1024 rows of context

typedef unsigned short ushort_t;
typedef __bf16 bf16x8 __attribute__((ext_vector_type(8)));
typedef float f32x4 __attribute__((ext_vector_type(4)));

__device__ __forceinline__ float bf2f(ushort_t u) {
  union { unsigned u; float f; } c; c.u = ((unsigned)u) << 16; return c.f;
}
__device__ __forceinline__ ushort_t f2bf(float f) {
  union { float f; unsigned u; } c; c.f = f;
  unsigned r = c.u + 0x7fffu + ((c.u >> 16) & 1u);
  return (ushort_t)(r >> 16);
}

__device__ __forceinline__ void load_lds16(const void* g, void* l) {
  __builtin_amdgcn_global_load_lds(
      (const __attribute__((address_space(1))) void*)g,
      (__attribute__((address_space(3))) void*)l, 16, 0, 0);
}

// ---------------- fp32 -> bf16 convert ----------------
__global__ __launch_bounds__(256) void cvt_f32_bf16(const float* __restrict__ in,
                                                    ushort_t* __restrict__ out, int n4) {
  int i = blockIdx.x * 256 + threadIdx.x;
  if (i >= n4) return;
  float4 v = *(const float4*)(in + 4ull * (size_t)i);
  ushort4 o;
  o.x = f2bf(v.x); o.y = f2bf(v.y); o.z = f2bf(v.z); o.w = f2bf(v.w);
  *(ushort4*)(out + 4ull * (size_t)i) = o;
}

// ============ 256x256 8-phase GEMM: C[M,N] = A[M,K] @ W[N,K]^T + bias ============
// 8 waves (2M x 4N), BK=64 as two k-slabs of 32. LDS: 2 buffers x 4 regions
// (B-s0, A-s0, B-s1, A-s1) x 16KB = 128 KiB. Stage stream 3 half-tiles ahead,
// vmcnt(6) before tile-end barrier; st_16x32 XOR swizzle (linear gload_lds dest,
// pre-swizzled global source, swizzled ds_read).
template <int OUT_F32>
__global__ __launch_bounds__(512, 2) void gemm_bt8(const ushort_t* __restrict__ A,
                                                   const ushort_t* __restrict__ W,
                                                   const float* __restrict__ bias,
                                                   void* __restrict__ Cout,
                                                   int M, int N, int K) {
  __shared__ ushort_t lds[65536];   // 128 KiB
  char* ldsc = (char*)lds;
  const int tid = threadIdx.x;
  const int lane = tid & 63, w = tid >> 6;
  const int g = lane >> 4, c = lane & 15;
  const int wm = w >> 2, wn = w & 3;
  const int ntn = N >> 8;
  const int nwg = gridDim.x;
  int bid = blockIdx.x;
  bid = (bid & 7) * (nwg >> 3) + (bid >> 3);   // XCD swizzle (nwg % 8 == 0)
  const int tm = bid / ntn, tn = bid % ntn;
  const size_t m0 = (size_t)tm * 256, n0 = (size_t)tn * 256;
  const ushort_t* Ab = A + m0 * (size_t)K;
  const ushort_t* Bb = W + n0 * (size_t)K;
  const int NT = K >> 6;

  // ---- staging constants (per-thread): linear LDS dest d, swizzled global src
  const int srow = tid >> 2;                               // row for chunk 0
  const int sgq  = (tid & 3) ^ (((tid >> 5) & 1) << 1);    // swizzled 16B-col group
  const size_t rb0 = (size_t)srow * K + (size_t)sgq * 8;
  const size_t rb1 = rb0 + (size_t)128 * K;
  const int d0 = tid * 16;                                 // linear dest byte

  // ---- ds_read byte offsets within a region (swizzled)
  int offA[8], offB[4];
#pragma unroll
  for (int m = 0; m < 8; ++m) {
    int row = wm * 128 + m * 16 + c;
    offA[m] = row * 64 + ((g * 16) ^ ((row & 8) << 2));
  }
#pragma unroll
  for (int n = 0; n < 4; ++n) {
    int row = wn * 64 + n * 16 + c;
    offB[n] = row * 64 + ((g * 16) ^ ((row & 8) << 2));
  }

  auto STAGE = [&](int h) {
    const int th = h >> 2, j = h & 3;
    const int kofs = th * 64 + ((j >> 1) << 5);
    const ushort_t* gsrc = ((j & 1) ? Ab : Bb) + kofs;
    const int dbase = ((th & 1) << 16) + (j << 14);
    load_lds16(gsrc + rb0, ldsc + dbase + d0);
    load_lds16(gsrc + rb1, ldsc + dbase + 8192 + d0);
  };

  f32x4 acc[8][4] = {};

  // prologue: tile0 (4 halves) + first 3 halves of tile1
#pragma unroll
  for (int h = 0; h < 7; ++h) STAGE(h);
  asm volatile("s_waitcnt vmcnt(6)" ::: "memory");
  __builtin_amdgcn_s_barrier();

  for (int t = 0; t < NT; ++t) {
    const int buf = (t & 1) << 2;
    bf16x8 a[4], a2[4], b[4];
    // ---- phase q0: k-slab0, A rows m0-3 + all B
#pragma unroll
    for (int m = 0; m < 4; ++m)
      a[m] = *(const bf16x8*)(ldsc + ((buf + 1) << 14) + offA[m]);
#pragma unroll
    for (int n = 0; n < 4; ++n)
      b[n] = *(const bf16x8*)(ldsc + ((buf + 0) << 14) + offB[n]);
    if (t < NT - 2) STAGE(4 * t + 7);
    else if (t == NT - 2) STAGE(4 * NT - 1);
    __builtin_amdgcn_s_barrier();
    asm volatile("s_waitcnt lgkmcnt(0)" ::: "memory");
    __builtin_amdgcn_sched_barrier(0);
    __builtin_amdgcn_s_setprio(1);
#pragma unroll
    for (int m = 0; m < 4; ++m)
#pragma unroll
      for (int n = 0; n < 4; ++n)
        acc[m][n] = __builtin_amdgcn_mfma_f32_16x16x32_bf16(a[m], b[n], acc[m][n], 0, 0, 0);
    __builtin_amdgcn_s_setprio(0);
    __builtin_amdgcn_s_barrier();
    // ---- phase q1: k-slab0, A rows m4-7
#pragma unroll
    for (int m = 0; m < 4; ++m)
      a2[m] = *(const bf16x8*)(ldsc + ((buf + 1) << 14) + offA[4 + m]);
    if (t < NT - 2) STAGE(4 * t + 8);
    __builtin_amdgcn_s_barrier();
    asm volatile("s_waitcnt lgkmcnt(0)" ::: "memory");
    __builtin_amdgcn_sched_barrier(0);
    __builtin_amdgcn_s_setprio(1);
#pragma unroll
    for (int m = 0; m < 4; ++m)
#pragma unroll
      for (int n = 0; n < 4; ++n)
        acc[4 + m][n] = __builtin_amdgcn_mfma_f32_16x16x32_bf16(a2[m], b[n], acc[4 + m][n], 0, 0, 0);
    __builtin_amdgcn_s_setprio(0);
    __builtin_amdgcn_s_barrier();
    // ---- phase q2: k-slab1, A rows m0-3 + all B
#pragma unroll
    for (int m = 0; m < 4; ++m)
      a[m] = *(const bf16x8*)(ldsc + ((buf + 3) << 14) + offA[m]);
#pragma unroll
    for (int n = 0; n < 4; ++n)
      b[n] = *(const bf16x8*)(ldsc + ((buf + 2) << 14) + offB[n]);
    if (t < NT - 2) STAGE(4 * t + 9);
    __builtin_amdgcn_s_barrier();
    asm volatile("s_waitcnt lgkmcnt(0)" ::: "memory");
    __builtin_amdgcn_sched_barrier(0);
    __builtin_amdgcn_s_setprio(1);
#pragma unroll
    for (int m = 0; m < 4; ++m)
#pragma unroll
      for (int n = 0; n < 4; ++n)
        acc[m][n] = __builtin_amdgcn_mfma_f32_16x16x32_bf16(a[m], b[n], acc[m][n], 0, 0, 0);
    __builtin_amdgcn_s_setprio(0);
    __builtin_amdgcn_s_barrier();
    // ---- phase q3: k-slab1, A rows m4-7
#pragma unroll
    for (int m = 0; m < 4; ++m)
      a2[m] = *(const bf16x8*)(ldsc + ((buf + 3) << 14) + offA[4 + m]);
    if (t < NT - 2) STAGE(4 * t + 10);
    __builtin_amdgcn_s_barrier();
    asm volatile("s_waitcnt lgkmcnt(0)" ::: "memory");
    __builtin_amdgcn_sched_barrier(0);
    __builtin_amdgcn_s_setprio(1);
#pragma unroll
    for (int m = 0; m < 4; ++m)
#pragma unroll
      for (int n = 0; n < 4; ++n)
        acc[4 + m][n] = __builtin_amdgcn_mfma_f32_16x16x32_bf16(a2[m], b[n], acc[4 + m][n], 0, 0, 0);
    __builtin_amdgcn_s_setprio(0);
    // tile-end: prove next tile landed BEFORE crossing the barrier
    if (t < NT - 2)      asm volatile("s_waitcnt vmcnt(6)" ::: "memory");
    else if (t == NT - 2) asm volatile("s_waitcnt vmcnt(0)" ::: "memory");
    __builtin_amdgcn_s_barrier();
  }

  // epilogue: C/D layout col=lane&15, row=(lane>>4)*4+reg
#pragma unroll
  for (int m = 0; m < 8; ++m) {
#pragma unroll
    for (int n = 0; n < 4; ++n) {
      size_t gm = m0 + wm * 128 + m * 16 + g * 4;
      size_t gn = n0 + wn * 64 + n * 16 + c;
      float bn = bias[gn];
#pragma unroll
      for (int r = 0; r < 4; ++r) {
        float v = acc[m][n][r] + bn;
        if (OUT_F32) ((float*)Cout)[(gm + r) * (size_t)N + gn] = v;
        else         ((ushort_t*)Cout)[(gm + r) * (size_t)N + gn] = f2bf(v);
      }
    }
  }
  (void)M;
}

// ---------------- 128x128 GEMM (m97 structure) for the small KV GEMM ----------------
template <int OUT_F32>
__global__ __launch_bounds__(256) void gemm_bt(const ushort_t* __restrict__ A,
                                               const ushort_t* __restrict__ W,
                                               const float* __restrict__ bias,
                                               void* __restrict__ Cout,
                                               int M, int N, int K) {
  __shared__ ushort_t sA[128 * 32];
  __shared__ ushort_t sB[128 * 32];
  const int tid = threadIdx.x;
  const int w = tid >> 6, lane = tid & 63;
  const int g = lane >> 4, c = lane & 15;
  const int ntn = N >> 7;
  const int nwg = gridDim.x;
  int bid = blockIdx.x;
  bid = (bid & 7) * (nwg >> 3) + (bid >> 3);
  const int tm = bid / ntn, tn = bid % ntn;
  const size_t m0 = (size_t)tm * 128, n0 = (size_t)tn * 128;
  const int wr = (w >> 1) * 64, wc = (w & 1) * 64;

  f32x4 acc[4][4] = {};

  const ushort_t* Abase = A + m0 * (size_t)K;
  const ushort_t* Bbase = W + n0 * (size_t)K;

  for (int k0 = 0; k0 < K; k0 += 32) {
    __syncthreads();
#pragma unroll
    for (int i = 0; i < 2; ++i) {
      int gid = i * 256 + tid;
      int row = gid >> 2, colE = (gid & 3) << 3;
      load_lds16(Abase + (size_t)row * K + k0 + colE, sA + i * 2048 + w * 512);
      load_lds16(Bbase + (size_t)row * K + k0 + colE, sB + i * 2048 + w * 512);
    }
    __syncthreads();
    bf16x8 a[4], b[4];
#pragma unroll
    for (int m = 0; m < 4; ++m)
      a[m] = *(const bf16x8*)(sA + (wr + m * 16 + c) * 32 + g * 8);
#pragma unroll
    for (int n = 0; n < 4; ++n)
      b[n] = *(const bf16x8*)(sB + (wc + n * 16 + c) * 32 + g * 8);
#pragma unroll
    for (int m = 0; m < 4; ++m)
#pragma unroll
      for (int n = 0; n < 4; ++n)
        acc[m][n] = __builtin_amdgcn_mfma_f32_16x16x32_bf16(a[m], b[n], acc[m][n], 0, 0, 0);
  }

#pragma unroll
  for (int m = 0; m < 4; ++m) {
#pragma unroll
    for (int n = 0; n < 4; ++n) {
      size_t gm = m0 + wr + m * 16 + g * 4;
      size_t gn = n0 + wc + n * 16 + c;
      float bn = bias[gn];
#pragma unroll
      for (int r = 0; r < 4; ++r) {
        float v = acc[m][n][r] + bn;
        if (OUT_F32) ((float*)Cout)[(gm + r) * (size_t)N + gn] = v;
        else         ((ushort_t*)Cout)[(gm + r) * (size_t)N + gn] = f2bf(v);
      }
    }
  }
}

// ---------------- RMSNorm (in place over ncols of each row) ----------------
__global__ __launch_bounds__(256) void rmsnorm_rows(ushort_t* __restrict__ x,
                                                    const float* __restrict__ gw,
                                                    int ncols, int stride) {
  const int row = blockIdx.x;
  ushort_t* p = x + (size_t)row * stride;
  const int tid = threadIdx.x;
  const int nch = ncols >> 3;
  float ss = 0.f;
  for (int ci = tid; ci < nch; ci += 256) {
    bf16x8 v = *(const bf16x8*)(p + ci * 8);
#pragma unroll
    for (int j = 0; j < 8; ++j) { float f = (float)v[j]; ss += f * f; }
  }
#pragma unroll
  for (int off = 1; off < 64; off <<= 1) ss += __shfl_xor(ss, off);
  __shared__ float sred[4];
  if ((tid & 63) == 0) sred[tid >> 6] = ss;
  __syncthreads();
  float tot = sred[0] + sred[1] + sred[2] + sred[3];
  float inv = rsqrtf(tot / (float)ncols + 1e-6f);
  for (int ci = tid; ci < nch; ci += 256) {
    bf16x8 v = *(const bf16x8*)(p + ci * 8);
    bf16x8 ov;
#pragma unroll
    for (int j = 0; j < 8; ++j) {
      float f = (float)v[j];
      ushort_t ob = f2bf(f * inv * gw[ci * 8 + j]);
      ov[j] = *(__bf16*)&ob;
    }
    *(bf16x8*)(p + ci * 8) = ov;
  }
}

// ---------------- V transpose: kv[:, DIM + h*HD + d] -> vt[bh][d][l] ----------------
__global__ __launch_bounds__(256) void transpose_v(const ushort_t* __restrict__ kv,
                                                   ushort_t* __restrict__ vt) {
  const int bh = blockIdx.y, b = bh / NH, h = bh % NH;
  const int l0 = blockIdx.x * 32;
  const ushort_t* src = kv + (size_t)b * L_LEN * (2 * DIM) + DIM + (size_t)h * HD;
  ushort_t* dst = vt + (size_t)bh * HD * L_LEN;
  __shared__ ushort_t tile[32][HD + 16];
  const int tid = threadIdx.x;
#pragma unroll
  for (int i = 0; i < 2; ++i) {
    int gid = i * 256 + tid;
    int r = gid >> 4, ce = (gid & 15) << 3;
    *(bf16x8*)(&tile[r][ce]) = *(const bf16x8*)(src + (size_t)(l0 + r) * (2 * DIM) + ce);
  }
  __syncthreads();
#pragma unroll
  for (int i = 0; i < 2; ++i) {
    int gid = i * 256 + tid;
    int d = gid >> 2, le = (gid & 3) << 3;
    bf16x8 v;
#pragma unroll
    for (int j = 0; j < 8; ++j) v[j] = *(__bf16*)&tile[le + j][d];
    *(bf16x8*)(dst + (size_t)d * L_LEN + l0 + le) = v;
  }
}

// ---------------- fused cross-attention ----------------
__global__ __launch_bounds__(256) void attn_fwd(const ushort_t* __restrict__ q,
                                                const ushort_t* __restrict__ kv,
                                                const ushort_t* __restrict__ vt,
                                                ushort_t* __restrict__ out) {
  const int bh = blockIdx.y, b = bh / NH, h = bh % NH;
  const int sBase = blockIdx.x * 64;
  const int tid = threadIdx.x, w = tid >> 6, lane = tid & 63;
  const int g = lane >> 4, c = lane & 15;
  const int qr0 = sBase + w * 16;

  const ushort_t* qbase = q + ((size_t)b * S_LEN + qr0) * DIM + (size_t)h * HD;
  const ushort_t* kbase = kv + (size_t)b * L_LEN * (2 * DIM) + (size_t)h * HD;
  const ushort_t* vbase = vt + (size_t)bh * HD * L_LEN;

  bf16x8 qa[4];
#pragma unroll
  for (int kk = 0; kk < 4; ++kk)
    qa[kk] = *(const bf16x8*)(qbase + (size_t)c * DIM + kk * 32 + g * 8);

  f32x4 oacc[8] = {};
  float mrun[4], lrun[4];
#pragma unroll
  for (int r = 0; r < 4; ++r) { mrun[r] = -3.0e38f; lrun[r] = 0.f; }

  const float sc = 0.08838834764831845f * 1.4426950408889634f;

  __shared__ ushort_t sP[4][16][32];

  for (int l0 = 0; l0 < L_LEN; l0 += 32) {
    f32x4 sv0 = {0.f, 0.f, 0.f, 0.f}, sv1 = {0.f, 0.f, 0.f, 0.f};
#pragma unroll
    for (int kk = 0; kk < 4; ++kk) {
      bf16x8 kb0 = *(const bf16x8*)(kbase + (size_t)(l0 + c) * (2 * DIM) + kk * 32 + g * 8);
      sv0 = __builtin_amdgcn_mfma_f32_16x16x32_bf16(qa[kk], kb0, sv0, 0, 0, 0);
      bf16x8 kb1 = *(const bf16x8*)(kbase + (size_t)(l0 + 16 + c) * (2 * DIM) + kk * 32 + g * 8);
      sv1 = __builtin_amdgcn_mfma_f32_16x16x32_bf16(qa[kk], kb1, sv1, 0, 0, 0);
    }
    float alpha[4];
#pragma unroll
    for (int r = 0; r < 4; ++r) {
      float a0 = sv0[r] * sc, a1 = sv1[r] * sc;
      float v = fmaxf(a0, a1);
      v = fmaxf(v, __shfl_xor(v, 1));
      v = fmaxf(v, __shfl_xor(v, 2));
      v = fmaxf(v, __shfl_xor(v, 4));
      v = fmaxf(v, __shfl_xor(v, 8));
      float mn = fmaxf(mrun[r], v);
      alpha[r] = exp2f(mrun[r] - mn);
      float p0 = exp2f(a0 - mn), p1 = exp2f(a1 - mn);
      float ps = p0 + p1;
      ps += __shfl_xor(ps, 1);
      ps += __shfl_xor(ps, 2);
      ps += __shfl_xor(ps, 4);
      ps += __shfl_xor(ps, 8);
      lrun[r] = lrun[r] * alpha[r] + ps;
      mrun[r] = mn;
      sP[w][g * 4 + r][c] = f2bf(p0);
      sP[w][g * 4 + r][16 + c] = f2bf(p1);
    }
#pragma unroll
    for (int t = 0; t < 8; ++t)
#pragma unroll
      for (int r = 0; r < 4; ++r) oacc[t][r] *= alpha[r];
    bf16x8 pa = *(const bf16x8*)(&sP[w][c][g * 8]);
#pragma unroll
    for (int t = 0; t < 8; ++t) {
      bf16x8 vb = *(const bf16x8*)(vbase + (size_t)(t * 16 + c) * L_LEN + l0 + g * 8);
      oacc[t] = __builtin_amdgcn_mfma_f32_16x16x32_bf16(pa, vb, oacc[t], 0, 0, 0);
    }
  }

  ushort_t* obase = out + ((size_t)b * S_LEN + qr0) * DIM + (size_t)h * HD;
#pragma unroll
  for (int t = 0; t < 8; ++t)
#pragma unroll
    for (int r = 0; r < 4; ++r) {
      float v = oacc[t][r] / lrun[r];
      obase[(size_t)(g * 4 + r) * DIM + t * 16 + c] = f2bf(v);
    }
}

// ---------------- host ----------------
extern "C" void kernel_launch(void* const* d_in, const int* in_sizes, int n_in,
                              void* d_out, int out_size, void* d_ws, size_t ws_size,
                              hipStream_t stream) {
  (void)in_sizes; (void)n_in; (void)out_size; (void)ws_size;
  const float* hidden_c = (const float*)d_in[0];
  const float* hidden_u = (const float*)d_in[1];
  const float* ctx_c    = (const float*)d_in[2];
  const float* ctx_u    = (const float*)d_in[3];
  const float* Wq  = (const float*)d_in[4];
  const float* bq  = (const float*)d_in[5];
  const float* Wkv = (const float*)d_in[6];
  const float* bkv = (const float*)d_in[7];
  const float* gq  = (const float*)d_in[8];
  const float* gk  = (const float*)d_in[9];
  const float* Wo  = (const float*)d_in[10];
  const float* bo  = (const float*)d_in[11];

  char* ws = (char*)d_ws;
  size_t off = 0;
  auto alloc = [&](size_t bytes) {
    char* p = ws + off; off += (bytes + 255) & ~(size_t)255; return p;
  };
  ushort_t* hbf  = (ushort_t*)alloc((size_t)MQ * DIM * 2);
  ushort_t* cbf  = (ushort_t*)alloc((size_t)ML * DIM * 2);
  ushort_t* wqb  = (ushort_t*)alloc((size_t)DIM * DIM * 2);
  ushort_t* wkvb = (ushort_t*)alloc((size_t)2 * DIM * DIM * 2);
  ushort_t* kvb  = (ushort_t*)alloc((size_t)ML * 2 * DIM * 2);
  ushort_t* vtb  = (ushort_t*)alloc((size_t)CBATCH * NH * HD * L_LEN * 2);
  ushort_t* qb   = (ushort_t*)d_out;

  auto cvt = [&](const float* in, ushort_t* o, size_t n) {
    int n4 = (int)(n >> 2);
    cvt_f32_bf16<<<dim3((n4 + 255) / 256), dim3(256), 0, stream>>>(in, o, n4);
  };
  cvt(hidden_c, hbf, (size_t)S_LEN * DIM);
  cvt(hidden_u, hbf + (size_t)S_LEN * DIM, (size_t)S_LEN * DIM);
  cvt(ctx_c, cbf, (size_t)L_LEN * DIM);
  cvt(ctx_u, cbf + (size_t)L_LEN * DIM, (size_t)L_LEN * DIM);
  cvt(Wq, wqb, (size_t)DIM * DIM);
  cvt(Wkv, wkvb, (size_t)2 * DIM * DIM);

  // Q = hidden @ Wq^T + bq  -> qb (bf16, in d_out space)   [256x256 8-phase]
  gemm_bt8<0><<<dim3((MQ / 256) * (DIM / 256)), dim3(512), 0, stream>>>(
      hbf, wqb, bq, (void*)qb, MQ, DIM, DIM);
  // KV = context @ Wkv^T + bkv -> kvb   [128x128]
  gemm_bt<0><<<dim3((ML / 128) * ((2 * DIM) / 128)), dim3(256), 0, stream>>>(
      cbf, wkvb, bkv, (void*)kvb, ML, 2 * DIM, DIM);
  // Wo -> bf16 (reuses wqb)
  cvt(Wo, wqb, (size_t)DIM * DIM);

  rmsnorm_rows<<<dim3(MQ), dim3(256), 0, stream>>>(qb, gq, DIM, DIM);
  rmsnorm_rows<<<dim3(ML), dim3(256), 0, stream>>>(kvb, gk, DIM, 2 * DIM);
  transpose_v<<<dim3(L_LEN / 32, CBATCH * NH), dim3(256), 0, stream>>>(kvb, vtb);

  attn_fwd<<<dim3(S_LEN / 64, CBATCH * NH), dim3(256), 0, stream>>>(qb, kvb, vtb, hbf);

  // out = attn_out @ Wo^T + bo -> d_out (fp32)   [256x256 8-phase]
  gemm_bt8<1><<<dim3((MQ / 256) * (DIM / 256)), dim3(512), 0, stream>>>(
      hbf, wqb, bo, d_out, MQ, DIM, DIM);
}

// Round 3
// 1581.236 us; speedup vs baseline: 1.4184x; 1.1612x over previous
//
#include <hip/hip_runtime.h>
#include <hip/hip_bf16.h>
#include <cstdint>
#include <cstddef>

#define DIM 5120
#define NH 40
#define HD 128
#define S_LEN 4096
#define L_LEN 512
#define CBATCH 2            // 2*B (cond + uncond)
#define MQ (CBATCH*S_LEN)   // 8192 rows of hidden
#define ML (CBATCH*L_LEN)   // 1024 rows of context

typedef unsigned short ushort_t;
typedef __bf16 bf16x8 __attribute__((ext_vector_type(8)));
typedef float f32x4 __attribute__((ext_vector_type(4)));
typedef float f32x16 __attribute__((ext_vector_type(16)));

__device__ __forceinline__ ushort_t f2bf(float f) {
  union { float f; unsigned u; } c; c.f = f;
  unsigned r = c.u + 0x7fffu + ((c.u >> 16) & 1u);
  return (ushort_t)(r >> 16);
}

__device__ __forceinline__ void load_lds16(const void* g, void* l) {
  __builtin_amdgcn_global_load_lds(
      (const __attribute__((address_space(1))) void*)g,
      (__attribute__((address_space(3))) void*)l, 16, 0, 0);
}

// ---------------- fp32 -> bf16 convert ----------------
__global__ __launch_bounds__(256) void cvt_f32_bf16(const float* __restrict__ in,
                                                    ushort_t* __restrict__ out, int n4) {
  int i = blockIdx.x * 256 + threadIdx.x;
  if (i >= n4) return;
  float4 v = *(const float4*)(in + 4ull * (size_t)i);
  ushort4 o;
  o.x = f2bf(v.x); o.y = f2bf(v.y); o.z = f2bf(v.z); o.w = f2bf(v.w);
  *(ushort4*)(out + 4ull * (size_t)i) = o;
}

// ============ 256x256 8-phase GEMM: C[M,N] = A[M,K] @ W[N,K]^T + bias ============
template <int OUT_F32>
__global__ __launch_bounds__(512, 2) void gemm_bt8(const ushort_t* __restrict__ A,
                                                   const ushort_t* __restrict__ W,
                                                   const float* __restrict__ bias,
                                                   void* __restrict__ Cout,
                                                   int M, int N, int K) {
  __shared__ ushort_t lds[65536];   // 128 KiB
  char* ldsc = (char*)lds;
  const int tid = threadIdx.x;
  const int lane = tid & 63, w = tid >> 6;
  const int g = lane >> 4, c = lane & 15;
  const int wm = w >> 2, wn = w & 3;
  const int ntn = N >> 8;
  const int nwg = gridDim.x;
  int bid = blockIdx.x;
  bid = (bid & 7) * (nwg >> 3) + (bid >> 3);   // XCD swizzle (nwg % 8 == 0)
  const int tm = bid / ntn, tn = bid % ntn;
  const size_t m0 = (size_t)tm * 256, n0 = (size_t)tn * 256;
  const ushort_t* Ab = A + m0 * (size_t)K;
  const ushort_t* Bb = W + n0 * (size_t)K;
  const int NT = K >> 6;

  const int srow = tid >> 2;
  const int sgq  = (tid & 3) ^ (((tid >> 5) & 1) << 1);
  const size_t rb0 = (size_t)srow * K + (size_t)sgq * 8;
  const size_t rb1 = rb0 + (size_t)128 * K;
  const int d0 = tid * 16;

  int offA[8], offB[4];
#pragma unroll
  for (int m = 0; m < 8; ++m) {
    int row = wm * 128 + m * 16 + c;
    offA[m] = row * 64 + ((g * 16) ^ ((row & 8) << 2));
  }
#pragma unroll
  for (int n = 0; n < 4; ++n) {
    int row = wn * 64 + n * 16 + c;
    offB[n] = row * 64 + ((g * 16) ^ ((row & 8) << 2));
  }

  auto STAGE = [&](int h) {
    const int th = h >> 2, j = h & 3;
    const int kofs = th * 64 + ((j >> 1) << 5);
    const ushort_t* gsrc = ((j & 1) ? Ab : Bb) + kofs;
    const int dbase = ((th & 1) << 16) + (j << 14);
    load_lds16(gsrc + rb0, ldsc + dbase + d0);
    load_lds16(gsrc + rb1, ldsc + dbase + 8192 + d0);
  };

  f32x4 acc[8][4] = {};

#pragma unroll
  for (int h = 0; h < 7; ++h) STAGE(h);
  asm volatile("s_waitcnt vmcnt(6)" ::: "memory");
  __builtin_amdgcn_s_barrier();

  for (int t = 0; t < NT; ++t) {
    const int buf = (t & 1) << 2;
    bf16x8 a[4], a2[4], b[4];
#pragma unroll
    for (int m = 0; m < 4; ++m)
      a[m] = *(const bf16x8*)(ldsc + ((buf + 1) << 14) + offA[m]);
#pragma unroll
    for (int n = 0; n < 4; ++n)
      b[n] = *(const bf16x8*)(ldsc + ((buf + 0) << 14) + offB[n]);
    if (t < NT - 2) STAGE(4 * t + 7);
    else if (t == NT - 2) STAGE(4 * NT - 1);
    __builtin_amdgcn_s_barrier();
    asm volatile("s_waitcnt lgkmcnt(0)" ::: "memory");
    __builtin_amdgcn_sched_barrier(0);
    __builtin_amdgcn_s_setprio(1);
#pragma unroll
    for (int m = 0; m < 4; ++m)
#pragma unroll
      for (int n = 0; n < 4; ++n)
        acc[m][n] = __builtin_amdgcn_mfma_f32_16x16x32_bf16(a[m], b[n], acc[m][n], 0, 0, 0);
    __builtin_amdgcn_s_setprio(0);
    __builtin_amdgcn_s_barrier();
#pragma unroll
    for (int m = 0; m < 4; ++m)
      a2[m] = *(const bf16x8*)(ldsc + ((buf + 1) << 14) + offA[4 + m]);
    if (t < NT - 2) STAGE(4 * t + 8);
    __builtin_amdgcn_s_barrier();
    asm volatile("s_waitcnt lgkmcnt(0)" ::: "memory");
    __builtin_amdgcn_sched_barrier(0);
    __builtin_amdgcn_s_setprio(1);
#pragma unroll
    for (int m = 0; m < 4; ++m)
#pragma unroll
      for (int n = 0; n < 4; ++n)
        acc[4 + m][n] = __builtin_amdgcn_mfma_f32_16x16x32_bf16(a2[m], b[n], acc[4 + m][n], 0, 0, 0);
    __builtin_amdgcn_s_setprio(0);
    __builtin_amdgcn_s_barrier();
#pragma unroll
    for (int m = 0; m < 4; ++m)
      a[m] = *(const bf16x8*)(ldsc + ((buf + 3) << 14) + offA[m]);
#pragma unroll
    for (int n = 0; n < 4; ++n)
      b[n] = *(const bf16x8*)(ldsc + ((buf + 2) << 14) + offB[n]);
    if (t < NT - 2) STAGE(4 * t + 9);
    __builtin_amdgcn_s_barrier();
    asm volatile("s_waitcnt lgkmcnt(0)" ::: "memory");
    __builtin_amdgcn_sched_barrier(0);
    __builtin_amdgcn_s_setprio(1);
#pragma unroll
    for (int m = 0; m < 4; ++m)
#pragma unroll
      for (int n = 0; n < 4; ++n)
        acc[m][n] = __builtin_amdgcn_mfma_f32_16x16x32_bf16(a[m], b[n], acc[m][n], 0, 0, 0);
    __builtin_amdgcn_s_setprio(0);
    __builtin_amdgcn_s_barrier();
#pragma unroll
    for (int m = 0; m < 4; ++m)
      a2[m] = *(const bf16x8*)(ldsc + ((buf + 3) << 14) + offA[4 + m]);
    if (t < NT - 2) STAGE(4 * t + 10);
    __builtin_amdgcn_s_barrier();
    asm volatile("s_waitcnt lgkmcnt(0)" ::: "memory");
    __builtin_amdgcn_sched_barrier(0);
    __builtin_amdgcn_s_setprio(1);
#pragma unroll
    for (int m = 0; m < 4; ++m)
#pragma unroll
      for (int n = 0; n < 4; ++n)
        acc[4 + m][n] = __builtin_amdgcn_mfma_f32_16x16x32_bf16(a2[m], b[n], acc[4 + m][n], 0, 0, 0);
    __builtin_amdgcn_s_setprio(0);
    if (t < NT - 2)      asm volatile("s_waitcnt vmcnt(6)" ::: "memory");
    else if (t == NT - 2) asm volatile("s_waitcnt vmcnt(0)" ::: "memory");
    __builtin_amdgcn_s_barrier();
  }

#pragma unroll
  for (int m = 0; m < 8; ++m) {
#pragma unroll
    for (int n = 0; n < 4; ++n) {
      size_t gm = m0 + wm * 128 + m * 16 + g * 4;
      size_t gn = n0 + wn * 64 + n * 16 + c;
      float bn = bias[gn];
#pragma unroll
      for (int r = 0; r < 4; ++r) {
        float v = acc[m][n][r] + bn;
        if (OUT_F32) ((float*)Cout)[(gm + r) * (size_t)N + gn] = v;
        else         ((ushort_t*)Cout)[(gm + r) * (size_t)N + gn] = f2bf(v);
      }
    }
  }
  (void)M;
}

// ---------------- 128x128 GEMM (m97 structure) for the small KV GEMM ----------------
template <int OUT_F32>
__global__ __launch_bounds__(256) void gemm_bt(const ushort_t* __restrict__ A,
                                               const ushort_t* __restrict__ W,
                                               const float* __restrict__ bias,
                                               void* __restrict__ Cout,
                                               int M, int N, int K) {
  __shared__ ushort_t sA[128 * 32];
  __shared__ ushort_t sB[128 * 32];
  const int tid = threadIdx.x;
  const int w = tid >> 6, lane = tid & 63;
  const int g = lane >> 4, c = lane & 15;
  const int ntn = N >> 7;
  const int nwg = gridDim.x;
  int bid = blockIdx.x;
  bid = (bid & 7) * (nwg >> 3) + (bid >> 3);
  const int tm = bid / ntn, tn = bid % ntn;
  const size_t m0 = (size_t)tm * 128, n0 = (size_t)tn * 128;
  const int wr = (w >> 1) * 64, wc = (w & 1) * 64;

  f32x4 acc[4][4] = {};

  const ushort_t* Abase = A + m0 * (size_t)K;
  const ushort_t* Bbase = W + n0 * (size_t)K;

  for (int k0 = 0; k0 < K; k0 += 32) {
    __syncthreads();
#pragma unroll
    for (int i = 0; i < 2; ++i) {
      int gid = i * 256 + tid;
      int row = gid >> 2, colE = (gid & 3) << 3;
      load_lds16(Abase + (size_t)row * K + k0 + colE, sA + i * 2048 + w * 512);
      load_lds16(Bbase + (size_t)row * K + k0 + colE, sB + i * 2048 + w * 512);
    }
    __syncthreads();
    bf16x8 a[4], b[4];
#pragma unroll
    for (int m = 0; m < 4; ++m)
      a[m] = *(const bf16x8*)(sA + (wr + m * 16 + c) * 32 + g * 8);
#pragma unroll
    for (int n = 0; n < 4; ++n)
      b[n] = *(const bf16x8*)(sB + (wc + n * 16 + c) * 32 + g * 8);
#pragma unroll
    for (int m = 0; m < 4; ++m)
#pragma unroll
      for (int n = 0; n < 4; ++n)
        acc[m][n] = __builtin_amdgcn_mfma_f32_16x16x32_bf16(a[m], b[n], acc[m][n], 0, 0, 0);
  }

#pragma unroll
  for (int m = 0; m < 4; ++m) {
#pragma unroll
    for (int n = 0; n < 4; ++n) {
      size_t gm = m0 + wr + m * 16 + g * 4;
      size_t gn = n0 + wc + n * 16 + c;
      float bn = bias[gn];
#pragma unroll
      for (int r = 0; r < 4; ++r) {
        float v = acc[m][n][r] + bn;
        if (OUT_F32) ((float*)Cout)[(gm + r) * (size_t)N + gn] = v;
        else         ((ushort_t*)Cout)[(gm + r) * (size_t)N + gn] = f2bf(v);
      }
    }
  }
}

// ---------------- RMSNorm (in place; optional extra output scale) ----------------
__global__ __launch_bounds__(256) void rmsnorm_rows(ushort_t* __restrict__ x,
                                                    const float* __restrict__ gw,
                                                    int ncols, int stride, float oscale) {
  const int row = blockIdx.x;
  ushort_t* p = x + (size_t)row * stride;
  const int tid = threadIdx.x;
  const int nch = ncols >> 3;
  float ss = 0.f;
  for (int ci = tid; ci < nch; ci += 256) {
    bf16x8 v = *(const bf16x8*)(p + ci * 8);
#pragma unroll
    for (int j = 0; j < 8; ++j) { float f = (float)v[j]; ss += f * f; }
  }
#pragma unroll
  for (int off = 1; off < 64; off <<= 1) ss += __shfl_xor(ss, off);
  __shared__ float sred[4];
  if ((tid & 63) == 0) sred[tid >> 6] = ss;
  __syncthreads();
  float tot = sred[0] + sred[1] + sred[2] + sred[3];
  float inv = rsqrtf(tot / (float)ncols + 1e-6f) * oscale;
  for (int ci = tid; ci < nch; ci += 256) {
    bf16x8 v = *(const bf16x8*)(p + ci * 8);
    bf16x8 ov;
#pragma unroll
    for (int j = 0; j < 8; ++j) {
      float f = (float)v[j];
      ushort_t ob = f2bf(f * inv * gw[ci * 8 + j]);
      ov[j] = *(__bf16*)&ob;
    }
    *(bf16x8*)(p + ci * 8) = ov;
  }
}

// ---------------- V transpose: kv[:, DIM + h*HD + d] -> vt[bh][d][l] ----------------
__global__ __launch_bounds__(256) void transpose_v(const ushort_t* __restrict__ kv,
                                                   ushort_t* __restrict__ vt) {
  const int bh = blockIdx.y, b = bh / NH, h = bh % NH;
  const int l0 = blockIdx.x * 32;
  const ushort_t* src = kv + (size_t)b * L_LEN * (2 * DIM) + DIM + (size_t)h * HD;
  ushort_t* dst = vt + (size_t)bh * HD * L_LEN;
  __shared__ ushort_t tile[32][HD + 16];
  const int tid = threadIdx.x;
#pragma unroll
  for (int i = 0; i < 2; ++i) {
    int gid = i * 256 + tid;
    int r = gid >> 4, ce = (gid & 15) << 3;
    *(bf16x8*)(&tile[r][ce]) = *(const bf16x8*)(src + (size_t)(l0 + r) * (2 * DIM) + ce);
  }
  __syncthreads();
#pragma unroll
  for (int i = 0; i < 2; ++i) {
    int gid = i * 256 + tid;
    int d = gid >> 2, le = (gid & 3) << 3;
    bf16x8 v;
#pragma unroll
    for (int j = 0; j < 8; ++j) v[j] = *(__bf16*)&tile[le + j][d];
    *(bf16x8*)(dst + (size_t)d * L_LEN + l0 + le) = v;
  }
}

// ---------------- fused cross-attention (swapped-QK^T, in-register softmax) ----------
// grid: (S_LEN/128, CBATCH*NH); 4 waves; 32 q-rows per wave; 32x32x16 MFMA.
// Q pre-scaled by (1/sqrt(Dh))*log2(e) in its RMSNorm -> scores in exp2 domain.
__global__ __launch_bounds__(256) void attn_fwd(const ushort_t* __restrict__ q,
                                                const ushort_t* __restrict__ kv,
                                                const ushort_t* __restrict__ vt,
                                                ushort_t* __restrict__ out) {
  const int bh = blockIdx.y, b = bh / NH, h = bh % NH;
  const int tid = threadIdx.x, w = tid >> 6, lane = tid & 63;
  const int lq = lane & 31, hi = lane >> 5;
  const int qr0 = blockIdx.x * 128 + w * 32;

  const ushort_t* qrow  = q  + ((size_t)b * S_LEN + qr0 + lq) * DIM + (size_t)h * HD + hi * 8;
  const ushort_t* krow  = kv + (size_t)b * L_LEN * (2 * DIM) + (size_t)h * HD
                             + (size_t)lq * (2 * DIM) + hi * 8;
  const ushort_t* vrow  = vt + (size_t)bh * HD * L_LEN + (size_t)lq * L_LEN + hi * 8;

  // Q B-frags: n=q=lane&31, k=d = ks*16 + hi*8 + e
  bf16x8 qf[8];
#pragma unroll
  for (int ks = 0; ks < 8; ++ks) qf[ks] = *(const bf16x8*)(qrow + ks * 16);

  f32x16 o[4];
#pragma unroll
  for (int ch = 0; ch < 4; ++ch) o[ch] = 0.f;
  float m = -1e30f, lsum = 0.f;

  for (int l0 = 0; l0 < L_LEN; l0 += 32) {
    // ---- QK^T (swapped): S^T[l][q]; lane holds col q, 16 l-rows
    f32x16 sv = 0.f;
#pragma unroll
    for (int ks = 0; ks < 8; ++ks) {
      bf16x8 kf = *(const bf16x8*)(krow + (size_t)l0 * (2 * DIM) + ks * 16);
      sv = __builtin_amdgcn_mfma_f32_32x32x16_bf16(kf, qf[ks], sv, 0, 0, 0);
    }
    // ---- in-lane max over 16, then cross-half combine
    float pm = fmaxf(fmaxf(fmaxf(sv[0], sv[1]), fmaxf(sv[2], sv[3])),
                     fmaxf(fmaxf(sv[4], sv[5]), fmaxf(sv[6], sv[7])));
    pm = fmaxf(pm, fmaxf(fmaxf(fmaxf(sv[8], sv[9]), fmaxf(sv[10], sv[11])),
                         fmaxf(fmaxf(sv[12], sv[13]), fmaxf(sv[14], sv[15]))));
    pm = fmaxf(pm, __shfl_xor(pm, 32));
    // ---- defer-max (T13, theta=8 in log2 domain)
    if (__ballot(pm > m + 8.0f)) {
      float mn = fmaxf(m, pm);
      float al = __builtin_amdgcn_exp2f(m - mn);
      lsum *= al;
      m = mn;
#pragma unroll
      for (int r = 0; r < 16; ++r) {
        float ar = __shfl(al, (r & 3) + 8 * (r >> 2) + 4 * hi);
        o[0][r] *= ar; o[1][r] *= ar; o[2][r] *= ar; o[3][r] *= ar;
      }
    }
    // ---- P = exp2(S - m), in-lane sum
    float p[16]; float ls = 0.f;
#pragma unroll
    for (int r = 0; r < 16; ++r) { p[r] = __builtin_amdgcn_exp2f(sv[r] - m); ls += p[r]; }
    ls += __shfl_xor(ls, 32);
    lsum += ls;
    // ---- pack P -> A-frags for PV (2 k-steps of 16 l each)
    bf16x8 pa[2];
#pragma unroll
    for (int ks = 0; ks < 2; ++ks) {
      unsigned w0 = (unsigned)f2bf(p[8 * ks + 0]) | ((unsigned)f2bf(p[8 * ks + 1]) << 16);
      unsigned w1 = (unsigned)f2bf(p[8 * ks + 2]) | ((unsigned)f2bf(p[8 * ks + 3]) << 16);
      unsigned w2 = (unsigned)f2bf(p[8 * ks + 4]) | ((unsigned)f2bf(p[8 * ks + 5]) << 16);
      unsigned w3 = (unsigned)f2bf(p[8 * ks + 6]) | ((unsigned)f2bf(p[8 * ks + 7]) << 16);
      unsigned e0 = __shfl_xor((int)w0, 32), e1 = __shfl_xor((int)w1, 32);
      unsigned e2 = __shfl_xor((int)w2, 32), e3 = __shfl_xor((int)w3, 32);
      unsigned d0 = hi ? e2 : w0, d1 = hi ? e3 : w1;
      unsigned d2 = hi ? w2 : e0, d3 = hi ? w3 : e1;
      unsigned tmp[4] = {d0, d1, d2, d3};
      pa[ks] = *(const bf16x8*)tmp;
    }
    // ---- PV: O[q][d] += P[q][l] * Vt[d][l]
#pragma unroll
    for (int ch = 0; ch < 4; ++ch) {
#pragma unroll
      for (int ks = 0; ks < 2; ++ks) {
        bf16x8 vf = *(const bf16x8*)(vrow + (size_t)ch * 32 * L_LEN + l0 + ks * 16);
        o[ch] = __builtin_amdgcn_mfma_f32_32x32x16_bf16(pa[ks], vf, o[ch], 0, 0, 0);
      }
    }
  }

  // ---- epilogue: divide by lsum (per q-row broadcast), write bf16
  float inv[16];
#pragma unroll
  for (int r = 0; r < 16; ++r) {
    float lr = __shfl(lsum, (r & 3) + 8 * (r >> 2) + 4 * hi);
    inv[r] = 1.0f / lr;
  }
  ushort_t* ob = out + ((size_t)b * S_LEN + qr0) * DIM + (size_t)h * HD;
#pragma unroll
  for (int ch = 0; ch < 4; ++ch)
#pragma unroll
    for (int r = 0; r < 16; ++r) {
      int row = (r & 3) + 8 * (r >> 2) + 4 * hi;
      ob[(size_t)row * DIM + ch * 32 + lq] = f2bf(o[ch][r] * inv[r]);
    }
}

// ---------------- host ----------------
extern "C" void kernel_launch(void* const* d_in, const int* in_sizes, int n_in,
                              void* d_out, int out_size, void* d_ws, size_t ws_size,
                              hipStream_t stream) {
  (void)in_sizes; (void)n_in; (void)out_size; (void)ws_size;
  const float* hidden_c = (const float*)d_in[0];
  const float* hidden_u = (const float*)d_in[1];
  const float* ctx_c    = (const float*)d_in[2];
  const float* ctx_u    = (const float*)d_in[3];
  const float* Wq  = (const float*)d_in[4];
  const float* bq  = (const float*)d_in[5];
  const float* Wkv = (const float*)d_in[6];
  const float* bkv = (const float*)d_in[7];
  const float* gq  = (const float*)d_in[8];
  const float* gk  = (const float*)d_in[9];
  const float* Wo  = (const float*)d_in[10];
  const float* bo  = (const float*)d_in[11];

  char* ws = (char*)d_ws;
  size_t off = 0;
  auto alloc = [&](size_t bytes) {
    char* p = ws + off; off += (bytes + 255) & ~(size_t)255; return p;
  };
  ushort_t* hbf  = (ushort_t*)alloc((size_t)MQ * DIM * 2);
  ushort_t* cbf  = (ushort_t*)alloc((size_t)ML * DIM * 2);
  ushort_t* wqb  = (ushort_t*)alloc((size_t)DIM * DIM * 2);
  ushort_t* wkvb = (ushort_t*)alloc((size_t)2 * DIM * DIM * 2);
  ushort_t* kvb  = (ushort_t*)alloc((size_t)ML * 2 * DIM * 2);
  ushort_t* vtb  = (ushort_t*)alloc((size_t)CBATCH * NH * HD * L_LEN * 2);
  ushort_t* qb   = (ushort_t*)d_out;

  auto cvt = [&](const float* in, ushort_t* o, size_t n) {
    int n4 = (int)(n >> 2);
    cvt_f32_bf16<<<dim3((n4 + 255) / 256), dim3(256), 0, stream>>>(in, o, n4);
  };
  cvt(hidden_c, hbf, (size_t)S_LEN * DIM);
  cvt(hidden_u, hbf + (size_t)S_LEN * DIM, (size_t)S_LEN * DIM);
  cvt(ctx_c, cbf, (size_t)L_LEN * DIM);
  cvt(ctx_u, cbf + (size_t)L_LEN * DIM, (size_t)L_LEN * DIM);
  cvt(Wq, wqb, (size_t)DIM * DIM);
  cvt(Wkv, wkvb, (size_t)2 * DIM * DIM);

  gemm_bt8<0><<<dim3((MQ / 256) * (DIM / 256)), dim3(512), 0, stream>>>(
      hbf, wqb, bq, (void*)qb, MQ, DIM, DIM);
  gemm_bt<0><<<dim3((ML / 128) * ((2 * DIM) / 128)), dim3(256), 0, stream>>>(
      cbf, wkvb, bkv, (void*)kvb, ML, 2 * DIM, DIM);
  cvt(Wo, wqb, (size_t)DIM * DIM);

  // Q RMSNorm folds in attn scale * log2(e) so QK^T lands in exp2 domain
  const float qscale = 0.08838834764831845f * 1.4426950408889634f;
  rmsnorm_rows<<<dim3(MQ), dim3(256), 0, stream>>>(qb, gq, DIM, DIM, qscale);
  rmsnorm_rows<<<dim3(ML), dim3(256), 0, stream>>>(kvb, gk, DIM, 2 * DIM, 1.0f);
  transpose_v<<<dim3(L_LEN / 32, CBATCH * NH), dim3(256), 0, stream>>>(kvb, vtb);

  attn_fwd<<<dim3(S_LEN / 128, CBATCH * NH), dim3(256), 0, stream>>>(qb, kvb, vtb, hbf);

  gemm_bt8<1><<<dim3((MQ / 256) * (DIM / 256)), dim3(512), 0, stream>>>(
      hbf, wqb, bo, d_out, MQ, DIM, DIM);
}